// Round 20
// baseline (29809.796 us; speedup 1.0000x reference)
//
#include <hip/hip_runtime.h>

typedef unsigned u2v __attribute__((ext_vector_type(2)));

#define NS 99985

// ---- XOR-butterfly reduction, all-VALU builtins (proven R5-R17) ---------
template<int CTRL>
__device__ __forceinline__ float dpp_xadd(float v) {
    int s = __builtin_amdgcn_update_dpp(0, __float_as_int(v), CTRL, 0xF, 0xF, true);
    return v + __int_as_float(s);
}
#if __has_builtin(__builtin_amdgcn_permlane16_swap)
__device__ __forceinline__ float xor16_add(float v) {
    u2v r = __builtin_amdgcn_permlane16_swap((unsigned)__float_as_int(v),
                                             (unsigned)__float_as_int(v),
                                             false, false);
    return __int_as_float((int)r.x) + __int_as_float((int)r.y);
}
#else
__device__ __forceinline__ float xor16_add(float v) {
    int s = __builtin_amdgcn_ds_swizzle(__float_as_int(v), 0x401F);
    return v + __int_as_float(s);
}
#endif
__device__ __forceinline__ float red32(float v) {
    v = dpp_xadd<0xB1>(v); v = dpp_xadd<0x4E>(v);
    v = dpp_xadd<0x141>(v); v = dpp_xadd<0x140>(v);
    return xor16_add(v);
}

// ---- precompute: tab8[2n]=(s,C1r,C1i,C3r) tab8[2n+1]=(C3i,C2r,C2i,0) ----
// Ck_n = sum conj(u_{n-k})*u_n (0 for n<k); s_n = LRW/(sum|u_n|^2+eps)
__global__ void pre_tab8(const float* __restrict__ xre,
                         const float* __restrict__ xim,
                         float4* __restrict__ tab8, int ns) {
    int n = blockIdx.x * blockDim.x + threadIdx.x;
    if (n >= ns) return;
    const float* ar = xre + 4 * n;
    const float* ai = xim + 4 * n;
    float un = 0.f;
    #pragma unroll 8
    for (int k = 0; k < 64; ++k) un = fmaf(ar[k], ar[k], fmaf(ai[k], ai[k], un));
    float s = (1.0f / 64.0f) / (un + 1e-8f);
    float C[3][2] = {{0,0},{0,0},{0,0}};
    #pragma unroll
    for (int j = 1; j <= 3; ++j) {
        if (n >= j) {
            const float* pr = ar - 4 * j;
            const float* pi = ai - 4 * j;
            float cr = 0.f, ci = 0.f;
            #pragma unroll 8
            for (int k = 0; k < 64; ++k) {
                cr = fmaf(pr[k], ar[k], fmaf(pi[k], ai[k], cr));
                ci = fmaf(pr[k], ai[k], ci);
                ci = fmaf(-pi[k], ar[k], ci);
            }
            C[j - 1][0] = cr; C[j - 1][1] = ci;
        }
    }
    tab8[2 * n]     = make_float4(s, C[0][0], C[0][1], C[2][0]);
    tab8[2 * n + 1] = make_float4(C[2][1], C[1][0], C[1][1], 0.f);
}

// ---- 2-wave scan: lag-2 PRE base, consumer chain is pure-register -------
// LDS: sh[slot*2+half] = PRE slots (4); sh[8+slot*2+half] = ews slots (4).
__global__ __launch_bounds__(128, 1)
void ddlms_scan2(const float* __restrict__ xre,
                 const float* __restrict__ xim,
                 const float4* __restrict__ tab8,
                 float* __restrict__ out) {
    const int tid = (int)threadIdx.x;
    const int wid = tid >> 6;
    const int l = tid & 63;
    const int m = l & 31;
    const int half = l >> 5;

    constexpr float EPSv = 1e-8f;
    constexpr float LRF  = 1.0f / 128.0f;
    constexpr float LRB  = 1.0f / 2048.0f;
    const float B1 = 0.6324555320336759f;
    const float A1 = 0.31622776601683794f;
    const float A3 = 0.9486832980505138f;

    __shared__ float2 sh[16];
    if (tid < 16) sh[tid] = make_float2(0.f, 0.f);
    __syncthreads();

    float2* __restrict__ o2 = reinterpret_cast<float2*>(out);

    if (wid == 0) {
        // ---------------- consumer: scalar chain ----------------
        float fr = 1.f, fi = 0.f, br = 0.f, bi = 0.f, psr = 1.f, psj = 0.f;
        float e1r = 0.f, e1i = 0.f;          // ews_{n-1}
        float partR = 0.f, partI = 0.f;      // PRE_n + ews_{n-2}*C2_n

        // tab slots (entry e -> slot e&3): s, C1, C2 per slot
        float t0s=0,t0c1r=0,t0c1i=0,t0c2r=0,t0c2i=0;
        float t1s=0,t1c1r=0,t1c1i=0,t1c2r=0,t1c2i=0;
        float t2s=0,t2c1r=0,t2c1i=0,t2c2r=0,t2c2i=0;
        float t3s=0,t3c1r=0,t3c1i=0,t3c2r=0,t3c2i=0;
        auto LOADT = [&](int nn, float& s, float& c1r, float& c1i,
                         float& c2r, float& c2i) {
            if (nn > NS - 1) nn = NS - 1;
            float4 a = tab8[2 * nn], b = tab8[2 * nn + 1];
            s = a.x; c1r = a.y; c1i = a.z; c2r = b.y; c2i = b.z;
        };
        LOADT(0, t0s,t0c1r,t0c1i,t0c2r,t0c2i);
        LOADT(1, t1s,t1c1r,t1c1i,t1c2r,t1c2i);
        LOADT(2, t2s,t2c1r,t2c1i,t2c2r,t2c2i);

        auto W0 = [&](int n, float tCs, float tCc1r, float tCc1i,
                      float tNc2r, float tNc2i,
                      float& tFs, float& tFc1r, float& tFc1i,
                      float& tFc2r, float& tFc2i) {
            __syncthreads();
            // early-issue read of PRE_{n+1} (written phase n-1, barrier-ordered)
            float2 pN = sh[((n + 1) & 3) * 2 + half];

            // v_n = part_n + ews_{n-1}*C1_n   (pure-register chain start)
            float vr = fmaf(e1r, tCc1r, partR); vr = fmaf(-e1i, tCc1i, vr);
            float vi = fmaf(e1r, tCc1i, partI); vi = fmaf( e1i, tCc1r, vi);

            float kr = fmaf(vr, fr, -(vi * fi));
            float ki = fmaf(vr, fi,   vi * fr);
            float zr = kr + br, zi = ki + bi;
            if (m == 0) o2[2 * n + half] = make_float2(zr, zi);

            float magr = (fabsf(zr) > B1) ? A3 : A1;
            float dr   = (zr <= 0.f) ? -magr : magr;
            float magi = (fabsf(zi) > B1) ? A3 : A1;
            float di   = (zi <= 0.f) ? -magi : magi;

            float er = dr - zr, ei = di - zi;

            float v2  = fmaf(vr, vr, fmaf(vi, vi, EPSv));
            float rv  = __builtin_amdgcn_rcpf(v2);
            float gfr = fmaf(er, vr,   ei * vi)  * rv;
            float gfi = fmaf(ei, vr, -(er * vi)) * rv;
            float m2  = fmaf(gfr, gfr, gfi * gfi);
            float scf = fminf(1.f, 30.f * __builtin_amdgcn_rsqf(m2));
            float tf  = LRF * scf;

            float dbr = dr - br, dbi = di - bi;
            float ewr = fmaf(dbr, psr, -(dbi * psj)) - vr;
            float ewi = fmaf(dbr, psj,   dbi * psr)  - vi;

            float ewsr = tCs * ewr, ewsi = tCs * ewi;        // s_n*ew_n
            if (m == 0) sh[8 + (n & 3) * 2 + half] = make_float2(ewsr, ewsi);

            fr = fmaf(tf, gfr, fr); fi = fmaf(tf, gfi, fi);
            br = fmaf(LRB, er, br); bi = fmaf(LRB, ei, bi);

            float ff = fmaf(fr, fr, fi * fi);
            float rs = __builtin_amdgcn_rsqf(ff);
            psr = fr * rs; psj = -(fi * rs);

            // part_{n+1} = PRE_{n+1} + ews_{n-1}*C2_{n+1}  (uses pre-rotation e1)
            partR = fmaf(e1r, tNc2r, pN.x); partR = fmaf(-e1i, tNc2i, partR);
            partI = fmaf(e1r, tNc2i, pN.y); partI = fmaf( e1i, tNc2r, partI);

            e1r = ewsr; e1i = ewsi;                          // rotate history

            LOADT(n + 3, tFs, tFc1r, tFc1i, tFc2r, tFc2i);   // dist-3 prefetch
        };

        int n = 0;
        for (int it = 0; it < 24996; ++it) {   // 4*24996 = 99984 steps
            W0(n+0, t0s,t0c1r,t0c1i, t1c2r,t1c2i, t3s,t3c1r,t3c1i,t3c2r,t3c2i);
            W0(n+1, t1s,t1c1r,t1c1i, t2c2r,t2c2i, t0s,t0c1r,t0c1i,t0c2r,t0c2i);
            W0(n+2, t2s,t2c1r,t2c1i, t3c2r,t3c2i, t1s,t1c1r,t1c1i,t1c2r,t1c2i);
            W0(n+3, t3s,t3c1r,t3c1i, t0c2r,t0c2i, t2s,t2c1r,t2c1i,t2c2r,t2c2i);
            n += 4;
        }
        W0(99984, t0s,t0c1r,t0c1i, t1c2r,t1c2i,
                  t3s,t3c1r,t3c1i,t3c2r,t3c2i);  // tail (99984 % 4 == 0)
    } else {
        // ---------------- producer: w + lag-2 PRE ----------------
        float wAr = 0.f, wAi = 0.f, wBr = 0.f, wBi = 0.f;

        auto LOADU = [&](int nn, float& a, float& b_, float& c, float& d_) {
            if (nn > NS - 1) nn = NS - 1;
            const float* pr = xre + 4 * nn;
            const float* pi = xim + 4 * nn;
            a = pr[m]; c = pr[m + 32]; b_ = pi[m]; d_ = pi[m + 32];
        };
        // C3 tab slots (entry e -> slot e&3); init entries 2,3,4,5
        float c3r0=0,c3i0=0, c3r1=0,c3i1=0, c3r2=0,c3i2=0, c3r3=0,c3i3=0;
        auto LOADT3 = [&](int nn, float& c3r, float& c3i) {
            if (nn > NS - 1) nn = NS - 1;
            float4 a = tab8[2 * nn], b = tab8[2 * nn + 1];
            c3r = a.w; c3i = b.x;
        };
        LOADT3(2, c3r2, c3i2); LOADT3(3, c3r3, c3i3);
        LOADT3(4, c3r0, c3i0); LOADT3(5, c3r1, c3i1);

        // u slots (u_m -> slot m&3): init slot3=u_{-1}=0, slots0-2=u_0..u_2
        float u0Ar,u0Ai,u0Br,u0Bi, u1Ar,u1Ai,u1Br,u1Bi,
              u2Ar,u2Ai,u2Br,u2Bi, u3Ar,u3Ai,u3Br,u3Bi;
        u3Ar = u3Ai = u3Br = u3Bi = 0.f;
        LOADU(0, u0Ar, u0Ai, u0Br, u0Bi);
        LOADU(1, u1Ar, u1Ai, u1Br, u1Bi);
        LOADU(2, u2Ar, u2Ai, u2Br, u2Bi);

        auto W1 = [&](int k,
            float& uPAr, float& uPAi, float& uPBr, float& uPBi,   // u_{k-1}
            float uQAr, float uQAi, float uQBr, float uQBi,       // u_{k+2}
            float tQc3r, float tQc3i,                             // C3_{k+2}
            float& tFc3r, float& tFc3i) {
            __syncthreads();
            float2 ews = sh[8 + ((k - 1) & 3) * 2 + half];   // ews_{k-1}
            // pre2 = red(W_{k-1} * u_{k+2}) — products BEFORE w update;
            // the red32 DPP chain hides the ews LDS latency
            float prr = wAr * uQAr; prr = fmaf(-wAi, uQAi, prr);
            prr = fmaf(wBr, uQBr, prr); prr = fmaf(-wBi, uQBi, prr);
            float pri = wAr * uQAi; pri = fmaf( wAi, uQAr, pri);
            pri = fmaf(wBr, uQBi, pri); pri = fmaf( wBi, uQBr, pri);
            float pre2r = red32(prr), pre2i = red32(pri);
            // w_k = w_{k-1} + ews_{k-1} (x) conj(u_{k-1})
            wAr = fmaf(ews.x, uPAr, fmaf( ews.y, uPAi, wAr));
            wAi = fmaf(ews.y, uPAr, fmaf(-ews.x, uPAi, wAi));
            wBr = fmaf(ews.x, uPBr, fmaf( ews.y, uPBi, wBr));
            wBi = fmaf(ews.y, uPBr, fmaf(-ews.x, uPBi, wBi));
            // PRE_{k+2} = pre2 + ews_{k-1}*C3_{k+2} = red(W_k * u_{k+2})
            float PRr = fmaf(ews.x, tQc3r, fmaf(-ews.y, tQc3i, pre2r));
            float PRi = fmaf(ews.x, tQc3i, fmaf( ews.y, tQc3r, pre2i));
            if (m == 0) sh[((k + 2) & 3) * 2 + half] = make_float2(PRr, PRi);
            // prefetch u_{k+3} into the now-dead uP slot; tab entry k+6
            LOADU(k + 3, uPAr, uPAi, uPBr, uPBi);
            LOADT3(k + 6, tFc3r, tFc3i);
        };

        int k = 0;
        for (int it = 0; it < 24996; ++it) {
            W1(k+0, u3Ar,u3Ai,u3Br,u3Bi, u2Ar,u2Ai,u2Br,u2Bi,
                    c3r2,c3i2, c3r2,c3i2);
            W1(k+1, u0Ar,u0Ai,u0Br,u0Bi, u3Ar,u3Ai,u3Br,u3Bi,
                    c3r3,c3i3, c3r3,c3i3);
            W1(k+2, u1Ar,u1Ai,u1Br,u1Bi, u0Ar,u0Ai,u0Br,u0Bi,
                    c3r0,c3i0, c3r0,c3i0);
            W1(k+3, u2Ar,u2Ai,u2Br,u2Bi, u1Ar,u1Ai,u1Br,u1Bi,
                    c3r1,c3i1, c3r1,c3i1);
            k += 4;
        }
        W1(99984, u3Ar,u3Ai,u3Br,u3Bi, u2Ar,u2Ai,u2Br,u2Bi,
                  c3r2,c3i2, c3r2,c3i2);         // tail barrier match
    }
}

// ---- fallback: single-wave full scan, no workspace (R10-class) ----------
__global__ __launch_bounds__(64, 1)
void ddlms_scan_fb(const float* __restrict__ xre,
                   const float* __restrict__ xim,
                   float* __restrict__ out) {
    const int l = (int)threadIdx.x;
    const int m = l & 31;
    const int half = l >> 5;
    constexpr float EPSv = 1e-8f;
    constexpr float LRW  = 1.0f / 64.0f;
    constexpr float LRF  = 1.0f / 128.0f;
    constexpr float LRB  = 1.0f / 2048.0f;
    const float B1 = 0.6324555320336759f;
    const float A1 = 0.31622776601683794f;
    const float A3 = 0.9486832980505138f;
    float wAr=0.f, wAi=0.f, wBr=0.f, wBi=0.f;
    float fr=1.f, fi=0.f, br=0.f, bi=0.f, psr=1.f, psj=0.f;
    float vr=0.f, vi=0.f, ewPr=0.f, ewPi=0.f, sP=0.f;
    float2* __restrict__ o2 = reinterpret_cast<float2*>(out);
    auto LOADU = [&](int nn, float& a, float& b_, float& c, float& d_) {
        const float* pr = xre + 4 * nn;
        const float* pi = xim + 4 * nn;
        a = pr[m]; c = pr[m + 32]; b_ = pi[m]; d_ = pi[m + 32];
    };
    float pAr,pAi,pBr,pBi, qAr,qAi,qBr,qBi, rAr,rAi,rBr,rBi;
    pAr=pAi=pBr=pBi=0.f;
    LOADU(0, qAr,qAi,qBr,qBi);
    LOADU(1, rAr,rAi,rBr,rBi);
    auto STEP = [&](int n,
        float& uPAr, float& uPAi, float& uPBr, float& uPBi,
        float& uCAr, float& uCAi, float& uCBr, float& uCBi,
        float& uNAr, float& uNAi, float& uNBr, float& uNBi) {
        {
            float gr = ewPr * uPAr; gr = fmaf( ewPi, uPAi, gr);
            float gi = ewPi * uPAr; gi = fmaf(-ewPr, uPAi, gi);
            wAr = fmaf(sP, gr, wAr); wAi = fmaf(sP, gi, wAi);
            float hr = ewPr * uPBr; hr = fmaf( ewPi, uPBi, hr);
            float hi = ewPi * uPBr; hi = fmaf(-ewPr, uPBi, hi);
            wBr = fmaf(sP, hr, wBr); wBi = fmaf(sP, hi, wBi);
        }
        float basr, basi;
        {
            float prr = wAr * uNAr; prr = fmaf(-wAi, uNAi, prr);
            prr = fmaf(wBr, uNBr, prr); prr = fmaf(-wBi, uNBi, prr);
            float pri = wAr * uNAi; pri = fmaf( wAi, uNAr, pri);
            pri = fmaf(wBr, uNBi, pri); pri = fmaf( wBi, uNBr, pri);
            basr = red32(prr); basi = red32(pri);
        }
        float uu = uCAr*uCAr; uu = fmaf(uCAi,uCAi,uu);
        uu = fmaf(uCBr,uCBr,uu); uu = fmaf(uCBi,uCBi,uu);
        float sN = LRW * __builtin_amdgcn_rcpf(red32(uu) + EPSv);
        float ccr = uCAr*uNAr; ccr = fmaf(uCAi,uNAi,ccr);
        ccr = fmaf(uCBr,uNBr,ccr); ccr = fmaf(uCBi,uNBi,ccr);
        float cci = uCAr*uNAi; cci = fmaf(-uCAi,uNAr,cci);
        cci = fmaf(uCBr,uNBi,cci); cci = fmaf(-uCBi,uNBr,cci);
        float sCr = sN * red32(ccr), sCi = sN * red32(cci);
        float kr = fmaf(vr, fr, -(vi * fi));
        float ki = fmaf(vr, fi,   vi * fr);
        float zr = kr + br, zi = ki + bi;
        if (m == 0) o2[2 * n + half] = make_float2(zr, zi);
        float magr = (fabsf(zr) > B1) ? A3 : A1;
        float dr   = (zr <= 0.f) ? -magr : magr;
        float magi = (fabsf(zi) > B1) ? A3 : A1;
        float di   = (zi <= 0.f) ? -magi : magi;
        float er = dr - zr, ei = di - zi;
        float v2  = fmaf(vr, vr, fmaf(vi, vi, EPSv));
        float rv  = __builtin_amdgcn_rcpf(v2);
        float gfr = fmaf(er, vr,   ei * vi)  * rv;
        float gfi = fmaf(ei, vr, -(er * vi)) * rv;
        float m2  = fmaf(gfr, gfr, gfi * gfi);
        float scf = fminf(1.f, 30.f * __builtin_amdgcn_rsqf(m2));
        float tf  = LRF * scf;
        float dbr = dr - br, dbi = di - bi;
        float ewr = fmaf(dbr, psr, -(dbi * psj)) - vr;
        float ewi = fmaf(dbr, psj,   dbi * psr)  - vi;
        float Dr = fmaf(ewr, sCr, -(ewi * sCi));
        float Di = fmaf(ewr, sCi,   ewi * sCr);
        vr = basr + Dr; vi = basi + Di;
        fr = fmaf(tf, gfr, fr); fi = fmaf(tf, gfi, fi);
        br = fmaf(LRB, er, br); bi = fmaf(LRB, ei, bi);
        float ff = fmaf(fr, fr, fi * fi);
        float rs = __builtin_amdgcn_rsqf(ff);
        psr = fr * rs; psj = -(fi * rs);
        ewPr = ewr; ewPi = ewi; sP = sN;
        int nn = n + 2; if (nn > NS - 1) nn = NS - 1;
        LOADU(nn, uPAr, uPAi, uPBr, uPBi);
    };
    int n = 0;
    for (int it = 0; it < 33328; ++it) {
        STEP(n,     pAr,pAi,pBr,pBi,  qAr,qAi,qBr,qBi,  rAr,rAi,rBr,rBi);
        STEP(n + 1, qAr,qAi,qBr,qBi,  rAr,rAi,rBr,rBi,  pAr,pAi,pBr,pBi);
        STEP(n + 2, rAr,rAi,rBr,rBi,  pAr,pAi,pBr,pBi,  qAr,qAi,qBr,qBi);
        n += 3;
    }
    STEP(99984, pAr,pAi,pBr,pBi, qAr,qAi,qBr,qBi, rAr,rAi,rBr,rBi);
}

extern "C" void kernel_launch(void* const* d_in, const int* in_sizes, int n_in,
                              void* d_out, int out_size, void* d_ws, size_t ws_size,
                              hipStream_t stream) {
    const float* xre = (const float*)d_in[0];
    const float* xim = (const float*)d_in[1];
    float* out = (float*)d_out;

    if (ws_size >= (size_t)2 * NS * sizeof(float4)) {
        float4* tab8 = (float4*)d_ws;
        pre_tab8<<<(NS + 255) / 256, 256, 0, stream>>>(xre, xim, tab8, NS);
        ddlms_scan2<<<1, 128, 0, stream>>>(xre, xim, tab8, out);
    } else {
        ddlms_scan_fb<<<1, 64, 0, stream>>>(xre, xim, out);
    }
}

// Round 21
// 19800.443 us; speedup vs baseline: 1.5055x; 1.5055x over previous
//
#include <hip/hip_runtime.h>

typedef unsigned u2v __attribute__((ext_vector_type(2)));

#define NSTEPS 99985

// ---- XOR-butterfly reduction, all-VALU builtins (proven) ----------------
template<int CTRL>
__device__ __forceinline__ float dpp_xadd(float v) {
    int s = __builtin_amdgcn_update_dpp(0, __float_as_int(v), CTRL, 0xF, 0xF, true);
    return v + __int_as_float(s);
}
#if __has_builtin(__builtin_amdgcn_permlane16_swap)
__device__ __forceinline__ float xor16_add(float v) {
    u2v r = __builtin_amdgcn_permlane16_swap((unsigned)__float_as_int(v),
                                             (unsigned)__float_as_int(v),
                                             false, false);
    return __int_as_float((int)r.x) + __int_as_float((int)r.y);
}
#else
__device__ __forceinline__ float xor16_add(float v) {
    int s = __builtin_amdgcn_ds_swizzle(__float_as_int(v), 0x401F);
    return v + __int_as_float(s);
}
#endif
__device__ __forceinline__ float red32(float v) {
    v = dpp_xadd<0xB1>(v); v = dpp_xadd<0x4E>(v);
    v = dpp_xadd<0x141>(v); v = dpp_xadd<0x140>(v);
    return xor16_add(v);
}

// ---- parallel precompute: tab[n] = (s, s*Cr, s*Ci, 0) -------------------
__global__ void pre_tab(const float* __restrict__ xre,
                        const float* __restrict__ xim,
                        float4* __restrict__ tab, int ns) {
    int n = blockIdx.x * blockDim.x + threadIdx.x;
    if (n >= ns) return;
    const float* ar = xre + 4 * n;
    const float* ai = xim + 4 * n;
    float un = 0.f;
    #pragma unroll 8
    for (int k = 0; k < 64; ++k) un = fmaf(ar[k], ar[k], fmaf(ai[k], ai[k], un));
    float s = (1.0f / 64.0f) / (un + 1e-8f);
    float cr = 0.f, ci = 0.f;
    if (n + 1 < ns) {
        const float* br_ = ar + 4;
        const float* bi_ = ai + 4;
        #pragma unroll 8
        for (int k = 0; k < 64; ++k) {
            cr = fmaf(ar[k], br_[k], fmaf(ai[k], bi_[k], cr));
            ci = fmaf(ar[k], bi_[k], ci);
            ci = fmaf(-ai[k], br_[k], ci);
        }
    }
    tab[n] = make_float4(s, s * cr, s * ci, 0.f);
}

// ---- 2-wave producer/consumer scan --------------------------------------
// wave0 (consumer): scalar chain per half; wave1 (producer): w + base.
// LDS: sh[2p+h] = bas (parity p, half h); sh[4+2p+h] = ews = s*ew.
// One barrier/step; parity double-buffer removes intra-step races.
__global__ __launch_bounds__(128, 1)
void ddlms_scan2(const float* __restrict__ xre,
                 const float* __restrict__ xim,
                 const float4* __restrict__ tab,
                 float* __restrict__ out) {
    const int tid = (int)threadIdx.x;
    const int wid = tid >> 6;
    const int l = tid & 63;
    const int m = l & 31;
    const int half = l >> 5;

    constexpr float EPSv = 1e-8f;
    constexpr float LRF  = 1.0f / 128.0f;
    constexpr float LRB  = 1.0f / 2048.0f;
    const float B1 = 0.6324555320336759f;
    const float A1 = 0.31622776601683794f;
    const float A3 = 0.9486832980505138f;

    __shared__ float2 sh[8];
    if (tid < 8) sh[tid] = make_float2(0.f, 0.f);
    __syncthreads();

    float2* __restrict__ o2 = reinterpret_cast<float2*>(out);

    if (wid == 0) {
        // ---------------- consumer: scalar chain ----------------
        float fr = 1.f, fi = 0.f, br = 0.f, bi = 0.f, psr = 1.f, psj = 0.f;
        float ewPr = 0.f, ewPi = 0.f, sCPr = 0.f, sCPi = 0.f;
        float4 t0 = tab[0], t1 = tab[1], t2 = tab[2], t3;

        auto W0 = [&](int n, int P, float4& tC, float4& tF) {
            __syncthreads();
            float2 bas = sh[2 * P + half];                 // bas_n (broadcast)
            float Dr = fmaf(ewPr, sCPr, -(ewPi * sCPi));   // D_{n-1}
            float Di = fmaf(ewPr, sCPi,   ewPi * sCPr);
            float vr = bas.x + Dr, vi = bas.y + Di;        // v_n
            { int nn = n + 3; if (nn > NSTEPS - 1) nn = NSTEPS - 1; tF = tab[nn]; }

            float kr = fmaf(vr, fr, -(vi * fi));
            float ki = fmaf(vr, fi,   vi * fr);
            float zr = kr + br, zi = ki + bi;
            if (m == 0) o2[2 * n + half] = make_float2(zr, zi);

            float magr = (fabsf(zr) > B1) ? A3 : A1;
            float dr   = (zr <= 0.f) ? -magr : magr;
            float magi = (fabsf(zi) > B1) ? A3 : A1;
            float di   = (zi <= 0.f) ? -magi : magi;

            float er = dr - zr, ei = di - zi;

            float v2  = fmaf(vr, vr, fmaf(vi, vi, EPSv));
            float rv  = __builtin_amdgcn_rcpf(v2);
            float gfr = fmaf(er, vr,   ei * vi)  * rv;
            float gfi = fmaf(ei, vr, -(er * vi)) * rv;
            float m2  = fmaf(gfr, gfr, gfi * gfi);
            float scf = fminf(1.f, 30.f * __builtin_amdgcn_rsqf(m2));
            float tf  = LRF * scf;

            float dbr = dr - br, dbi = di - bi;
            float ewr = fmaf(dbr, psr, -(dbi * psj)) - vr;
            float ewi = fmaf(dbr, psj,   dbi * psr)  - vi;

            float ewsr = tC.x * ewr, ewsi = tC.x * ewi;    // s_n * ew_n
            if (m == 0) sh[4 + 2 * P + half] = make_float2(ewsr, ewsi);

            fr = fmaf(tf, gfr, fr); fi = fmaf(tf, gfi, fi);
            br = fmaf(LRB, er, br); bi = fmaf(LRB, ei, bi);

            float ff = fmaf(fr, fr, fi * fi);
            float rs = __builtin_amdgcn_rsqf(ff);
            psr = fr * rs; psj = -(fi * rs);

            ewPr = ewr; ewPi = ewi; sCPr = tC.y; sCPi = tC.z;
        };

        int n = 0;
        for (int it = 0; it < 24996; ++it) {   // 4*24996 = 99984
            W0(n + 0, 0, t0, t3);
            W0(n + 1, 1, t1, t0);
            W0(n + 2, 0, t2, t1);
            W0(n + 3, 1, t3, t2);
            n += 4;
        }
        W0(99984, 0, t0, t3);                  // tail (99984 % 4 == 0)
    } else {
        // ---------------- producer: w + base ----------------
        float wAr = 0.f, wAi = 0.f, wBr = 0.f, wBi = 0.f;

        auto LOADU = [&](int nn, float& a, float& b_, float& c, float& d_) {
            const float* pr = xre + 4 * nn;
            const float* pi = xim + 4 * nn;
            a = pr[m]; c = pr[m + 32]; b_ = pi[m]; d_ = pi[m + 32];
        };

        float u0Ar, u0Ai, u0Br, u0Bi, u1Ar, u1Ai, u1Br, u1Bi,
              u2Ar, u2Ai, u2Br, u2Bi, u3Ar, u3Ai, u3Br, u3Bi;
        u3Ar = u3Ai = u3Br = u3Bi = 0.f;       // u_{-1} (ews_{-1} = 0)
        LOADU(0, u0Ar, u0Ai, u0Br, u0Bi);
        LOADU(1, u1Ar, u1Ai, u1Br, u1Bi);
        LOADU(2, u2Ar, u2Ai, u2Br, u2Bi);

        auto W1 = [&](int n, int P,
            float& uPAr, float& uPAi, float& uPBr, float& uPBi,
            float& uNAr, float& uNAi, float& uNBr, float& uNBi) {
            __syncthreads();
            float2 ews = sh[4 + 2 * (1 - P) + half];       // ews_{n-1}
            // w += ews (x) conj(uP)   [association change: wander class]
            wAr = fmaf(ews.x, uPAr, fmaf( ews.y, uPAi, wAr));
            wAi = fmaf(ews.y, uPAr, fmaf(-ews.x, uPAi, wAi));
            wBr = fmaf(ews.x, uPBr, fmaf( ews.y, uPBi, wBr));
            wBi = fmaf(ews.y, uPBr, fmaf(-ews.x, uPBi, wBi));
            // distance-3 prefetch into the now-dead uP slot
            { int nn = n + 3; if (nn > NSTEPS - 1) nn = NSTEPS - 1;
              LOADU(nn, uPAr, uPAi, uPBr, uPBi); }
            // bas_{n+1} = red(w_n * u_{n+1})
            float prr = wAr * uNAr; prr = fmaf(-wAi, uNAi, prr);
            prr = fmaf(wBr, uNBr, prr); prr = fmaf(-wBi, uNBi, prr);
            float pri = wAr * uNAi; pri = fmaf( wAi, uNAr, pri);
            pri = fmaf(wBr, uNBi, pri); pri = fmaf( wBi, uNBr, pri);
            float basr = red32(prr), basi = red32(pri);
            if (m == 0) sh[2 * (1 - P) + half] = make_float2(basr, basi);
        };

        int n = 0;
        for (int it = 0; it < 24996; ++it) {
            W1(n + 0, 0, u3Ar,u3Ai,u3Br,u3Bi, u1Ar,u1Ai,u1Br,u1Bi);
            W1(n + 1, 1, u0Ar,u0Ai,u0Br,u0Bi, u2Ar,u2Ai,u2Br,u2Bi);
            W1(n + 2, 0, u1Ar,u1Ai,u1Br,u1Bi, u3Ar,u3Ai,u3Br,u3Bi);
            W1(n + 3, 1, u2Ar,u2Ai,u2Br,u2Bi, u0Ar,u0Ai,u0Br,u0Bi);
            n += 4;
        }
        W1(99984, 0, u3Ar,u3Ai,u3Br,u3Bi, u1Ar,u1Ai,u1Br,u1Bi);
    }
}

// ---- fallback: single-wave in-kernel scalars (no workspace) -------------
__global__ __launch_bounds__(64, 1)
void ddlms_scan_fb(const float* __restrict__ xre,
                   const float* __restrict__ xim,
                   float* __restrict__ out) {
    const int l = (int)threadIdx.x;
    const int m = l & 31;
    const int half = l >> 5;
    constexpr float EPSv = 1e-8f;
    constexpr float LRW  = 1.0f / 64.0f;
    constexpr float LRF  = 1.0f / 128.0f;
    constexpr float LRB  = 1.0f / 2048.0f;
    const float B1 = 0.6324555320336759f;
    const float A1 = 0.31622776601683794f;
    const float A3 = 0.9486832980505138f;
    float wAr=0.f, wAi=0.f, wBr=0.f, wBi=0.f;
    float fr=1.f, fi=0.f, br=0.f, bi=0.f, psr=1.f, psj=0.f;
    float vr=0.f, vi=0.f, ewPr=0.f, ewPi=0.f, sP=0.f;
    float2* __restrict__ o2 = reinterpret_cast<float2*>(out);
    auto LOADU = [&](int nn, float& a, float& b_, float& c, float& d_) {
        const float* pr = xre + 4 * nn;
        const float* pi = xim + 4 * nn;
        a = pr[m]; c = pr[m + 32]; b_ = pi[m]; d_ = pi[m + 32];
    };
    float pAr,pAi,pBr,pBi, qAr,qAi,qBr,qBi, rAr,rAi,rBr,rBi;
    pAr=pAi=pBr=pBi=0.f;
    LOADU(0, qAr,qAi,qBr,qBi);
    LOADU(1, rAr,rAi,rBr,rBi);
    auto STEP = [&](int n,
        float& uPAr, float& uPAi, float& uPBr, float& uPBi,
        float& uCAr, float& uCAi, float& uCBr, float& uCBi,
        float& uNAr, float& uNAi, float& uNBr, float& uNBi) {
        {
            float gr = ewPr * uPAr; gr = fmaf( ewPi, uPAi, gr);
            float gi = ewPi * uPAr; gi = fmaf(-ewPr, uPAi, gi);
            wAr = fmaf(sP, gr, wAr); wAi = fmaf(sP, gi, wAi);
            float hr = ewPr * uPBr; hr = fmaf( ewPi, uPBi, hr);
            float hi = ewPi * uPBr; hi = fmaf(-ewPr, uPBi, hi);
            wBr = fmaf(sP, hr, wBr); wBi = fmaf(sP, hi, wBi);
        }
        float basr, basi;
        {
            float prr = wAr * uNAr; prr = fmaf(-wAi, uNAi, prr);
            prr = fmaf(wBr, uNBr, prr); prr = fmaf(-wBi, uNBi, prr);
            float pri = wAr * uNAi; pri = fmaf( wAi, uNAr, pri);
            pri = fmaf(wBr, uNBi, pri); pri = fmaf( wBi, uNBr, pri);
            basr = red32(prr); basi = red32(pri);
        }
        float uu = uCAr*uCAr; uu = fmaf(uCAi,uCAi,uu);
        uu = fmaf(uCBr,uCBr,uu); uu = fmaf(uCBi,uCBi,uu);
        float sN = LRW * __builtin_amdgcn_rcpf(red32(uu) + EPSv);
        float ccr = uCAr*uNAr; ccr = fmaf(uCAi,uNAi,ccr);
        ccr = fmaf(uCBr,uNBr,ccr); ccr = fmaf(uCBi,uNBi,ccr);
        float cci = uCAr*uNAi; cci = fmaf(-uCAi,uNAr,cci);
        cci = fmaf(uCBr,uNBi,cci); cci = fmaf(-uCBi,uNBr,cci);
        float sCr = sN * red32(ccr), sCi = sN * red32(cci);
        float kr = fmaf(vr, fr, -(vi * fi));
        float ki = fmaf(vr, fi,   vi * fr);
        float zr = kr + br, zi = ki + bi;
        if (m == 0) o2[2 * n + half] = make_float2(zr, zi);
        float magr = (fabsf(zr) > B1) ? A3 : A1;
        float dr   = (zr <= 0.f) ? -magr : magr;
        float magi = (fabsf(zi) > B1) ? A3 : A1;
        float di   = (zi <= 0.f) ? -magi : magi;
        float er = dr - zr, ei = di - zi;
        float v2  = fmaf(vr, vr, fmaf(vi, vi, EPSv));
        float rv  = __builtin_amdgcn_rcpf(v2);
        float gfr = fmaf(er, vr,   ei * vi)  * rv;
        float gfi = fmaf(ei, vr, -(er * vi)) * rv;
        float m2  = fmaf(gfr, gfr, gfi * gfi);
        float scf = fminf(1.f, 30.f * __builtin_amdgcn_rsqf(m2));
        float tf  = LRF * scf;
        float dbr = dr - br, dbi = di - bi;
        float ewr = fmaf(dbr, psr, -(dbi * psj)) - vr;
        float ewi = fmaf(dbr, psj,   dbi * psr)  - vi;
        float Dr = fmaf(ewr, sCr, -(ewi * sCi));
        float Di = fmaf(ewr, sCi,   ewi * sCr);
        vr = basr + Dr; vi = basi + Di;
        fr = fmaf(tf, gfr, fr); fi = fmaf(tf, gfi, fi);
        br = fmaf(LRB, er, br); bi = fmaf(LRB, ei, bi);
        float ff = fmaf(fr, fr, fi * fi);
        float rs = __builtin_amdgcn_rsqf(ff);
        psr = fr * rs; psj = -(fi * rs);
        ewPr = ewr; ewPi = ewi; sP = sN;
        int nn = n + 2; if (nn > NSTEPS - 1) nn = NSTEPS - 1;
        LOADU(nn, uPAr, uPAi, uPBr, uPBi);
    };
    int n = 0;
    for (int it = 0; it < 33328; ++it) {
        STEP(n,     pAr,pAi,pBr,pBi,  qAr,qAi,qBr,qBi,  rAr,rAi,rBr,rBi);
        STEP(n + 1, qAr,qAi,qBr,qBi,  rAr,rAi,rBr,rBi,  pAr,pAi,pBr,pBi);
        STEP(n + 2, rAr,rAi,rBr,rBi,  pAr,pAi,pBr,pBi,  qAr,qAi,qBr,qBi);
        n += 3;
    }
    STEP(99984, pAr,pAi,pBr,pBi, qAr,qAi,qBr,qBi, rAr,rAi,rBr,rBi);
}

extern "C" void kernel_launch(void* const* d_in, const int* in_sizes, int n_in,
                              void* d_out, int out_size, void* d_ws, size_t ws_size,
                              hipStream_t stream) {
    const float* xre = (const float*)d_in[0];
    const float* xim = (const float*)d_in[1];
    float* out = (float*)d_out;

    if (ws_size >= (size_t)NSTEPS * sizeof(float4)) {
        float4* tab = (float4*)d_ws;
        pre_tab<<<(NSTEPS + 255) / 256, 256, 0, stream>>>(xre, xim, tab, NSTEPS);
        ddlms_scan2<<<1, 128, 0, stream>>>(xre, xim, tab, out);
    } else {
        ddlms_scan_fb<<<1, 64, 0, stream>>>(xre, xim, out);
    }
}